// Round 1
// baseline (865.946 us; speedup 1.0000x reference)
//
#include <hip/hip_runtime.h>
#include <stdint.h>

#define N_ROWS   2048
#define D_IN     1024
#define V_OUT    32000
#define SLEN_C   512
#define BATCH_C  32
#define CVOC     500
#define OUT_COLS 32500

#define MIN_NORM_F 1e-15f
#define PROJ_EPS_F 4e-3f

typedef __bf16 bf16x8_t __attribute__((ext_vector_type(8)));
typedef float  f32x4_t  __attribute__((ext_vector_type(4)));

__device__ __forceinline__ unsigned short f2bf(float f) {
    uint32_t b = __float_as_uint(f);
    b += 0x7FFFu + ((b >> 16) & 1u);           // round-to-nearest-even-ish
    return (unsigned short)(b >> 16);
}
__device__ __forceinline__ float bf2f(unsigned short u) {
    return __uint_as_float(((uint32_t)u) << 16);
}
__device__ __forceinline__ float wave_sum(float v) {
#pragma unroll
    for (int off = 32; off > 0; off >>= 1) v += __shfl_down(v, off, 64);
    return v;
}

// async global->LDS, 16B per lane, wave-uniform LDS base
__device__ __forceinline__ void load_lds16(const void* g, void* l) {
    __builtin_amdgcn_global_load_lds(
        (const __attribute__((address_space(1))) void*)g,
        (__attribute__((address_space(3))) void*)l, 16, 0, 0);
}

// ---------------- fp32 -> bf16 cast (vectorized) ----------------
__global__ __launch_bounds__(256)
void cast_f32_to_bf16(const float* __restrict__ src, unsigned short* __restrict__ dst, int n4) {
    int i = blockIdx.x * blockDim.x + threadIdx.x;
    int stride = gridDim.x * blockDim.x;
    for (; i < n4; i += stride) {
        float4 v = ((const float4*)src)[i];
        ushort4 o;
        o.x = f2bf(v.x); o.y = f2bf(v.y); o.z = f2bf(v.z); o.w = f2bf(v.w);
        ((ushort4*)dst)[i] = o;
    }
}

// ---------------- sum(b^2) ----------------
__global__ __launch_bounds__(1024)
void reduce_bsq(const float* __restrict__ bvec, float* __restrict__ out) {
    __shared__ float red[16];
    int tid = threadIdx.x;
    float s = 0.f;
    for (int i = tid; i < V_OUT; i += 1024) { float v = bvec[i]; s = fmaf(v, v, s); }
    s = wave_sum(s);
    int w = tid >> 6, l = tid & 63;
    if (l == 0) red[w] = s;
    __syncthreads();
    if (tid == 0) {
        float t = 0.f;
        for (int k = 0; k < 16; ++k) t += red[k];
        *out = t;
    }
}

// ---------------- per-row: g = artanh(min(||x||,1-1e-7))/||x||, p_copy ----------------
__global__ __launch_bounds__(256)
void row_stats(const float* __restrict__ hidden, const float* __restrict__ Wc,
               const float* __restrict__ bc_in, float* __restrict__ g_arr,
               float* __restrict__ pc_arr) {
    __shared__ float red[8];
    const int n = blockIdx.x;
    const int tid = threadIdx.x;
    float4 hv = *(const float4*)(hidden + (size_t)n * D_IN + tid * 4);
    float4 wv = *(const float4*)(Wc + tid * 4);
    float s = hv.x * hv.x + hv.y * hv.y + hv.z * hv.z + hv.w * hv.w;
    float d = hv.x * wv.x + hv.y * wv.y + hv.z * wv.z + hv.w * wv.w;
    s = wave_sum(s); d = wave_sum(d);
    const int w = tid >> 6, l = tid & 63;
    if (l == 0) { red[w] = s; red[4 + w] = d; }
    __syncthreads();
    if (tid == 0) {
        float S  = red[0] + red[1] + red[2] + red[3];
        float Dc = red[4] + red[5] + red[6] + red[7];
        float xn = fmaxf(sqrtf(S), MIN_NORM_F);
        float xc = fminf(xn, 1.f - 1e-7f);
        float at = 0.5f * logf((1.f + xc) / (1.f - xc));   // artanh
        float g = at / xn;
        // p_copy: mobius_matvec(Wc,x) -> mobius_add(.,bc) -> project -> sigmoid
        float mxn = fmaxf(fabsf(Dc), MIN_NORM_F);
        float res = tanhf(mxn * g) * (Dc / mxn);
        float bcv = bc_in[0];
        float x2 = res * res, y2 = bcv * bcv, xyv = res * bcv;
        float num = (1.f + 2.f * xyv + y2) * res + (1.f - x2) * bcv;
        float dn  = fmaxf(1.f + 2.f * xyv + x2 * y2, MIN_NORM_F);
        float o = num / dn;
        float an = fmaxf(fabsf(o), MIN_NORM_F);
        float mxp = 1.f - PROJ_EPS_F;
        if (an > mxp) o = o / an * mxp;
        pc_arr[n] = 1.f / (1.f + expf(-o));
        g_arr[n]  = g;
    }
}

// ---------------- bf16 MFMA GEMM: Mx[n][v] = sum_k H[n][k]*W[v][k] ----------------
// 128x128 tile, BK=64, 4 waves (2x2), 4x4 16x16x32 MFMA per wave, async staging.
__global__ __launch_bounds__(256)
void gemm_bt_bf16(const unsigned short* __restrict__ A,   // hidden bf16 [2048][1024]
                  const unsigned short* __restrict__ B,   // W bf16 [32000][1024]
                  float* __restrict__ Cout)               // d_out [2048][32500], cols 0..32000
{
    __shared__ unsigned short Als[128 * 64];
    __shared__ unsigned short Bls[128 * 64];
    const int tid  = threadIdx.x;
    const int wave = tid >> 6;
    const int lane = tid & 63;
    const int bn0 = blockIdx.x * 128;   // v dim, 250 tiles
    const int am0 = blockIdx.y * 128;   // n dim, 16 tiles

    const int srow  = lane >> 3;         // staging row-in-chunk 0..7
    const int skoff = (lane & 7) * 8;    // staging k elem offset
    const int fr = lane & 15;            // fragment row
    const int fk = (lane >> 4) * 8;      // fragment k offset
    const int wm = (wave >> 1) * 64;
    const int wn = (wave & 1) * 64;

    f32x4_t acc[4][4] = {};

    for (int kt = 0; kt < D_IN; kt += 64) {
#pragma unroll
        for (int q = 0; q < 4; ++q) {
            const int r0 = wave * 8 + q * 32;
            load_lds16(A + (size_t)(am0 + r0 + srow) * D_IN + kt + skoff, &Als[r0 * 64]);
            load_lds16(B + (size_t)(bn0 + r0 + srow) * D_IN + kt + skoff, &Bls[r0 * 64]);
        }
        __syncthreads();   // waits vmcnt(0) before barrier
#pragma unroll
        for (int kk = 0; kk < 64; kk += 32) {
            bf16x8_t af[4], bfr[4];
#pragma unroll
            for (int i = 0; i < 4; ++i)
                af[i] = *(const bf16x8_t*)&Als[(wm + i * 16 + fr) * 64 + kk + fk];
#pragma unroll
            for (int j = 0; j < 4; ++j)
                bfr[j] = *(const bf16x8_t*)&Bls[(wn + j * 16 + fr) * 64 + kk + fk];
#pragma unroll
            for (int i = 0; i < 4; ++i)
#pragma unroll
                for (int j = 0; j < 4; ++j)
                    acc[i][j] = __builtin_amdgcn_mfma_f32_16x16x32_bf16(af[i], bfr[j], acc[i][j], 0, 0, 0);
        }
        __syncthreads();
    }

    // C/D layout: col = lane&15, row = (lane>>4)*4 + reg   [measured m89/m91]
    const int cm = (lane >> 4) * 4;
    const int cn = lane & 15;
#pragma unroll
    for (int i = 0; i < 4; ++i) {
#pragma unroll
        for (int j = 0; j < 4; ++j) {
            const int mg = am0 + wm + i * 16 + cm;
            const int ng = bn0 + wn + j * 16 + cn;
            float* cp = Cout + (size_t)mg * OUT_COLS + ng;
#pragma unroll
            for (int r = 0; r < 4; ++r) cp[(size_t)r * OUT_COLS] = acc[i][j][r];
        }
    }
}

// ---------------- fused mobius_add + project + softmax epilogue (in-place on d_out row) ----
// logit_i = P*Mx_i + Q*b_i with per-row P,Q from S1=sum Mx^2, S2=sum Mx*b, Sb=sum b^2.
// |logit| <= 0.996 (poincare ball) -> skip max pass; pad column -> prob 0.
__global__ __launch_bounds__(1024)
void softmax_epi(float* __restrict__ Cout, const float* __restrict__ bvec,
                 const float* __restrict__ g_arr, const float* __restrict__ pc_arr,
                 const float* __restrict__ sb_ptr, const int* __restrict__ pad_ptr) {
    __shared__ unsigned short mxls[V_OUT];   // bf16 row cache, 64000 B
    __shared__ float red[32];
    __shared__ float bcast[4];
    const int n = blockIdx.x;
    const int tid = threadIdx.x;
    float* row = Cout + (size_t)n * OUT_COLS;
    const int pad = *pad_ptr;

    float s1 = 0.f, s2 = 0.f;
    for (int i = tid * 4; i < V_OUT; i += 4096) {
        float4 m  = *(const float4*)(row + i);
        float4 bv = *(const float4*)(bvec + i);
        s1 += m.x * m.x + m.y * m.y + m.z * m.z + m.w * m.w;
        s2 += m.x * bv.x + m.y * bv.y + m.z * bv.z + m.w * bv.w;
        ushort4 pk;
        pk.x = f2bf(m.x); pk.y = f2bf(m.y); pk.z = f2bf(m.z); pk.w = f2bf(m.w);
        *(ushort4*)&mxls[i] = pk;
    }
    s1 = wave_sum(s1); s2 = wave_sum(s2);
    const int w = tid >> 6, l = tid & 63;
    if (l == 0) { red[w] = s1; red[16 + w] = s2; }
    __syncthreads();
    if (tid == 0) {
        float a = 0.f, c2 = 0.f;
        for (int k = 0; k < 16; ++k) { a += red[k]; c2 += red[16 + k]; }
        bcast[0] = a; bcast[1] = c2;
    }
    __syncthreads();
    const float S1 = bcast[0], S2 = bcast[1];
    const float Sb = *sb_ptr;
    const float g  = g_arr[n];
    const float r   = fmaxf(sqrtf(S1), MIN_NORM_F);
    const float t   = tanhf(r * g);          // tanh(Mx_norm/x_norm * artanh(x_norm))
    const float smv = t / r;                 // matvec scale
    const float x2 = smv * smv * S1;
    const float xy = smv * S2;
    const float y2 = Sb;
    const float den = fmaxf(1.f + 2.f * xy + x2 * y2, MIN_NORM_F);
    float P = (1.f + 2.f * xy + y2) * smv / den;
    float Q = (1.f - x2) / den;
    const float nrm = fmaxf(sqrtf(P * P * S1 + 2.f * P * Q * S2 + Q * Q * Sb), MIN_NORM_F);
    const float mxp = 1.f - PROJ_EPS_F;
    if (nrm > mxp) { const float f = mxp / nrm; P *= f; Q *= f; }

    float z = 0.f;
    for (int i = tid * 4; i < V_OUT; i += 4096) {
        ushort4 mu = *(const ushort4*)&mxls[i];
        float4 bv  = *(const float4*)(bvec + i);
        float e0 = __expf(P * bf2f(mu.x) + Q * bv.x);
        float e1 = __expf(P * bf2f(mu.y) + Q * bv.y);
        float e2 = __expf(P * bf2f(mu.z) + Q * bv.z);
        float e3 = __expf(P * bf2f(mu.w) + Q * bv.w);
        if (i + 0 == pad) e0 = 0.f;
        if (i + 1 == pad) e1 = 0.f;
        if (i + 2 == pad) e2 = 0.f;
        if (i + 3 == pad) e3 = 0.f;
        z += (e0 + e1) + (e2 + e3);
    }
    z = wave_sum(z);
    if (l == 0) red[w] = z;
    __syncthreads();
    if (tid == 0) {
        float a = 0.f;
        for (int k = 0; k < 16; ++k) a += red[k];
        bcast[2] = a;
    }
    __syncthreads();
    const float scale = (1.f - pc_arr[n]) / bcast[2];
    for (int i = tid * 4; i < V_OUT; i += 4096) {
        ushort4 mu = *(const ushort4*)&mxls[i];
        float4 bv  = *(const float4*)(bvec + i);
        float4 o;
        o.x = (i + 0 == pad) ? 0.f : __expf(P * bf2f(mu.x) + Q * bv.x) * scale;
        o.y = (i + 1 == pad) ? 0.f : __expf(P * bf2f(mu.y) + Q * bv.y) * scale;
        o.z = (i + 2 == pad) ? 0.f : __expf(P * bf2f(mu.z) + Q * bv.z) * scale;
        o.w = (i + 3 == pad) ? 0.f : __expf(P * bf2f(mu.w) + Q * bv.w) * scale;
        *(float4*)(row + i) = o;
    }
}

// ---------------- copy path: out[t*32+b][32000+c] = pc * sum_s attn[t*32+b][s]*src[s][b][c] ----
__global__ __launch_bounds__(128)
void copy_einsum(const float* __restrict__ attn, const float* __restrict__ src_map,
                 const float* __restrict__ pc_arr, float* __restrict__ Cout) {
    __shared__ float atile[32][128];
    const int tid = threadIdx.x;
    const int cc = blockIdx.x;        // 0..3  (c chunk of 128)
    const int b  = blockIdx.y;        // 0..31
    const int t0 = blockIdx.z * 32;   // 0 or 32
    const int c = cc * 128 + tid;
    const bool cv = (c < CVOC);

    float acc[32];
#pragma unroll
    for (int t = 0; t < 32; ++t) acc[t] = 0.f;

    for (int s0 = 0; s0 < SLEN_C; s0 += 128) {
        __syncthreads();
        for (int idx = tid; idx < 32 * 128; idx += 128) {
            const int t = idx >> 7, s = idx & 127;
            atile[t][s] = attn[(size_t)((t0 + t) * BATCH_C + b) * SLEN_C + s0 + s];
        }
        __syncthreads();
        for (int j = 0; j < 128; j += 4) {
            float sv0 = 0.f, sv1 = 0.f, sv2 = 0.f, sv3 = 0.f;
            if (cv) {
                const float* sp = src_map + (size_t)(s0 + j) * (BATCH_C * CVOC) + b * CVOC + c;
                sv0 = sp[0];
                sv1 = sp[BATCH_C * CVOC];
                sv2 = sp[2 * BATCH_C * CVOC];
                sv3 = sp[3 * BATCH_C * CVOC];
            }
#pragma unroll
            for (int t = 0; t < 32; ++t) {
                const float4 av = *(const float4*)&atile[t][j];
                acc[t] = fmaf(av.x, sv0, acc[t]);
                acc[t] = fmaf(av.y, sv1, acc[t]);
                acc[t] = fmaf(av.z, sv2, acc[t]);
                acc[t] = fmaf(av.w, sv3, acc[t]);
            }
        }
    }
    if (cv) {
#pragma unroll
        for (int t = 0; t < 32; ++t) {
            const int n = (t0 + t) * BATCH_C + b;
            Cout[(size_t)n * OUT_COLS + V_OUT + c] = acc[t] * pc_arr[n];
        }
    }
}

extern "C" void kernel_launch(void* const* d_in, const int* in_sizes, int n_in,
                              void* d_out, int out_size, void* d_ws, size_t ws_size,
                              hipStream_t stream) {
    const float* hidden  = (const float*)d_in[0];
    const float* attn    = (const float*)d_in[1];
    const float* src_map = (const float*)d_in[2];
    const float* W       = (const float*)d_in[3];
    const float* bvec    = (const float*)d_in[4];
    const float* Wc      = (const float*)d_in[5];
    const float* bc      = (const float*)d_in[6];
    const int*   padp    = (const int*)d_in[7];
    float* out = (float*)d_out;

    const int wb_elems = V_OUT * D_IN;    // 32,768,000
    const int hb_elems = N_ROWS * D_IN;   //  2,097,152
    unsigned short* Wb = (unsigned short*)d_ws;
    unsigned short* Hb = Wb + wb_elems;
    float* g_arr  = (float*)(Hb + hb_elems);
    float* pc_arr = g_arr + N_ROWS;
    float* sb     = pc_arr + N_ROWS;
    // ws bytes used: 65,536,000 + 4,194,304 + 2*8192 + 4 ~= 69.8 MB

    cast_f32_to_bf16<<<4000, 256, 0, stream>>>(W, Wb, wb_elems / 4);
    cast_f32_to_bf16<<<512, 256, 0, stream>>>(hidden, Hb, hb_elems / 4);
    reduce_bsq<<<1, 1024, 0, stream>>>(bvec, sb);
    row_stats<<<N_ROWS, 256, 0, stream>>>(hidden, Wc, bc, g_arr, pc_arr);

    dim3 ggrid(V_OUT / 128, N_ROWS / 128);   // (250, 16)
    gemm_bt_bf16<<<ggrid, 256, 0, stream>>>(Hb, Wb, out);

    softmax_epi<<<N_ROWS, 1024, 0, stream>>>(out, bvec, g_arr, pc_arr, sb, padp);

    dim3 egrid(4, BATCH_C, 2);
    copy_einsum<<<egrid, 128, 0, stream>>>(attn, src_map, pc_arr, out);
}

// Round 2
// 800.156 us; speedup vs baseline: 1.0822x; 1.0822x over previous
//
#include <hip/hip_runtime.h>
#include <stdint.h>

#define N_ROWS   2048
#define D_IN     1024
#define V_OUT    32000
#define SLEN_C   512
#define BATCH_C  32
#define CVOC     500
#define OUT_COLS 32500

#define MIN_NORM_F 1e-15f
#define PROJ_EPS_F 4e-3f

typedef __bf16 bf16x8_t __attribute__((ext_vector_type(8)));
typedef float  f32x4_t  __attribute__((ext_vector_type(4)));
typedef unsigned short ushort8_t __attribute__((ext_vector_type(8)));

__device__ __forceinline__ unsigned short f2bf(float f) {
    uint32_t b = __float_as_uint(f);
    b += 0x7FFFu + ((b >> 16) & 1u);           // round-to-nearest-even
    return (unsigned short)(b >> 16);
}
__device__ __forceinline__ float bf2f(unsigned short u) {
    return __uint_as_float(((uint32_t)u) << 16);
}
__device__ __forceinline__ float wave_sum(float v) {
#pragma unroll
    for (int off = 32; off > 0; off >>= 1) v += __shfl_down(v, off, 64);
    return v;
}

// async global->LDS, 16B per lane, wave-uniform LDS base
__device__ __forceinline__ void load_lds16(const void* g, void* l) {
    __builtin_amdgcn_global_load_lds(
        (const __attribute__((address_space(1))) void*)g,
        (__attribute__((address_space(3))) void*)l, 16, 0, 0);
}

// ---------------- fp32 -> bf16 cast (vectorized) ----------------
__global__ __launch_bounds__(256)
void cast_f32_to_bf16(const float* __restrict__ src, unsigned short* __restrict__ dst, int n4) {
    int i = blockIdx.x * blockDim.x + threadIdx.x;
    int stride = gridDim.x * blockDim.x;
    for (; i < n4; i += stride) {
        float4 v = ((const float4*)src)[i];
        ushort4 o;
        o.x = f2bf(v.x); o.y = f2bf(v.y); o.z = f2bf(v.z); o.w = f2bf(v.w);
        ((ushort4*)dst)[i] = o;
    }
}

// ---------------- per-row: g = artanh(min(||x||,1-1e-7))/||x||, p_copy ----------------
__global__ __launch_bounds__(256)
void row_stats(const float* __restrict__ hidden, const float* __restrict__ Wc,
               const float* __restrict__ bc_in, float* __restrict__ g_arr,
               float* __restrict__ pc_arr) {
    __shared__ float red[8];
    const int n = blockIdx.x;
    const int tid = threadIdx.x;
    float4 hv = *(const float4*)(hidden + (size_t)n * D_IN + tid * 4);
    float4 wv = *(const float4*)(Wc + tid * 4);
    float s = hv.x * hv.x + hv.y * hv.y + hv.z * hv.z + hv.w * hv.w;
    float d = hv.x * wv.x + hv.y * wv.y + hv.z * wv.z + hv.w * wv.w;
    s = wave_sum(s); d = wave_sum(d);
    const int w = tid >> 6, l = tid & 63;
    if (l == 0) { red[w] = s; red[4 + w] = d; }
    __syncthreads();
    if (tid == 0) {
        float S  = red[0] + red[1] + red[2] + red[3];
        float Dc = red[4] + red[5] + red[6] + red[7];
        float xn = fmaxf(sqrtf(S), MIN_NORM_F);
        float xc = fminf(xn, 1.f - 1e-7f);
        float at = 0.5f * logf((1.f + xc) / (1.f - xc));   // artanh
        float g = at / xn;
        float mxn = fmaxf(fabsf(Dc), MIN_NORM_F);
        float res = tanhf(mxn * g) * (Dc / mxn);
        float bcv = bc_in[0];
        float x2 = res * res, y2 = bcv * bcv, xyv = res * bcv;
        float num = (1.f + 2.f * xyv + y2) * res + (1.f - x2) * bcv;
        float dn  = fmaxf(1.f + 2.f * xyv + x2 * y2, MIN_NORM_F);
        float o = num / dn;
        float an = fmaxf(fabsf(o), MIN_NORM_F);
        float mxp = 1.f - PROJ_EPS_F;
        if (an > mxp) o = o / an * mxp;
        pc_arr[n] = 1.f / (1.f + expf(-o));
        g_arr[n]  = g;
    }
}

// ---------------- bf16 MFMA GEMM: Mx[n][v] = sum_k H[n][k]*W[v][k] ----------------
// 128x128 tile, BK=64, 4 waves (2x2), 4x4 16x16x32 MFMA per wave.
// 1D grid of 4000 with supertile swizzle: all 16 n-tiles fastest, then 25
// v-tiles per supertile (400 blocks) -> concurrent working set = A(4MB)+B(6.5MB),
// LLC-resident -> B streamed from HBM once instead of 8x.
// Output: bf16, written into the first 64000 B of each d_out row (aliased;
// epilogue caches whole row in LDS before overwriting with fp32 probs).
__global__ __launch_bounds__(256)
void gemm_bt_bf16(const unsigned short* __restrict__ A,   // hidden bf16 [2048][1024]
                  const unsigned short* __restrict__ B,   // W bf16 [32000][1024]
                  unsigned short* __restrict__ Cb)        // bf16 rows, stride OUT_COLS*2
{
    __shared__ unsigned short Als[128 * 64];
    __shared__ unsigned short Bls[128 * 64];
    const int tid  = threadIdx.x;
    const int wave = tid >> 6;
    const int lane = tid & 63;
    const int f   = blockIdx.x;
    const int st  = f / 400;             // supertile 0..9
    const int loc = f - st * 400;
    const int am0 = (loc & 15) * 128;              // n-tile (fastest)
    const int bn0 = (st * 25 + (loc >> 4)) * 128;  // v-tile

    const int srow  = lane >> 3;         // staging row-in-chunk 0..7
    const int skoff = (lane & 7) * 8;    // staging k elem offset
    const int fr = lane & 15;            // fragment row
    const int fk = (lane >> 4) * 8;      // fragment k offset
    const int wm = (wave >> 1) * 64;
    const int wn = (wave & 1) * 64;

    f32x4_t acc[4][4] = {};

    for (int kt = 0; kt < D_IN; kt += 64) {
#pragma unroll
        for (int q = 0; q < 4; ++q) {
            const int r0 = wave * 8 + q * 32;
            load_lds16(A + (size_t)(am0 + r0 + srow) * D_IN + kt + skoff, &Als[r0 * 64]);
            load_lds16(B + (size_t)(bn0 + r0 + srow) * D_IN + kt + skoff, &Bls[r0 * 64]);
        }
        __syncthreads();
#pragma unroll
        for (int kk = 0; kk < 64; kk += 32) {
            bf16x8_t af[4], bfr[4];
#pragma unroll
            for (int i = 0; i < 4; ++i)
                af[i] = *(const bf16x8_t*)&Als[(wm + i * 16 + fr) * 64 + kk + fk];
#pragma unroll
            for (int j = 0; j < 4; ++j)
                bfr[j] = *(const bf16x8_t*)&Bls[(wn + j * 16 + fr) * 64 + kk + fk];
#pragma unroll
            for (int i = 0; i < 4; ++i)
#pragma unroll
                for (int j = 0; j < 4; ++j)
                    acc[i][j] = __builtin_amdgcn_mfma_f32_16x16x32_bf16(af[i], bfr[j], acc[i][j], 0, 0, 0);
        }
        __syncthreads();
    }

    // C/D layout: col = lane&15, row = (lane>>4)*4 + reg
    const int cm = (lane >> 4) * 4;
    const int cn = lane & 15;
#pragma unroll
    for (int i = 0; i < 4; ++i) {
#pragma unroll
        for (int j = 0; j < 4; ++j) {
            const int mg = am0 + wm + i * 16 + cm;
            const int ng = bn0 + wn + j * 16 + cn;
            unsigned short* cp = Cb + (size_t)mg * (OUT_COLS * 2) + ng;
#pragma unroll
            for (int r = 0; r < 4; ++r)
                cp[(size_t)r * (OUT_COLS * 2)] = f2bf(acc[i][j][r]);
        }
    }
}

// ---------------- fused mobius_add + project + softmax epilogue ----------------
// Reads bf16 Mx row (aliased at start of its own d_out row), caches in LDS,
// computes per-row P,Q (incl. Sb = sum b^2 folded into pass 1), exp once
// (bf16 back into LDS, pad zeroed), then scales + writes fp32 probs in-place.
__global__ __launch_bounds__(1024)
void softmax_epi(float* __restrict__ Cout, const float* __restrict__ bvec,
                 const float* __restrict__ g_arr, const float* __restrict__ pc_arr,
                 const int* __restrict__ pad_ptr) {
    __shared__ unsigned short mxls[V_OUT];   // bf16 row cache, 64000 B
    __shared__ float red[48];
    __shared__ float bcast[4];
    const int n = blockIdx.x;
    const int tid = threadIdx.x;
    float* row = Cout + (size_t)n * OUT_COLS;
    const unsigned short* rowb = (const unsigned short*)row;   // bf16 Mx alias
    const int pad = *pad_ptr;

    float s1 = 0.f, s2 = 0.f, s3 = 0.f;
    for (int i = tid * 8; i < V_OUT; i += 8192) {
        ushort8_t mu = *(const ushort8_t*)(rowb + i);
        float4 b0 = *(const float4*)(bvec + i);
        float4 b1 = *(const float4*)(bvec + i + 4);
        float m0 = bf2f(mu[0]), m1 = bf2f(mu[1]), m2 = bf2f(mu[2]), m3 = bf2f(mu[3]);
        float m4 = bf2f(mu[4]), m5 = bf2f(mu[5]), m6 = bf2f(mu[6]), m7 = bf2f(mu[7]);
        s1 += (m0*m0 + m1*m1 + m2*m2 + m3*m3) + (m4*m4 + m5*m5 + m6*m6 + m7*m7);
        s2 += (m0*b0.x + m1*b0.y + m2*b0.z + m3*b0.w) + (m4*b1.x + m5*b1.y + m6*b1.z + m7*b1.w);
        s3 += (b0.x*b0.x + b0.y*b0.y + b0.z*b0.z + b0.w*b0.w)
            + (b1.x*b1.x + b1.y*b1.y + b1.z*b1.z + b1.w*b1.w);
        *(ushort8_t*)&mxls[i] = mu;
    }
    s1 = wave_sum(s1); s2 = wave_sum(s2); s3 = wave_sum(s3);
    const int w = tid >> 6, l = tid & 63;
    if (l == 0) { red[w] = s1; red[16 + w] = s2; red[32 + w] = s3; }
    __syncthreads();
    if (tid == 0) {
        float S1 = 0.f, S2 = 0.f, Sb = 0.f;
        for (int k = 0; k < 16; ++k) { S1 += red[k]; S2 += red[16 + k]; Sb += red[32 + k]; }
        const float g  = g_arr[n];
        const float r   = fmaxf(sqrtf(S1), MIN_NORM_F);
        const float t   = tanhf(r * g);
        const float smv = t / r;                 // mobius_matvec scale
        const float x2 = smv * smv * S1;
        const float xy = smv * S2;
        const float den = fmaxf(1.f + 2.f * xy + x2 * Sb, MIN_NORM_F);
        float P = (1.f + 2.f * xy + Sb) * smv / den;
        float Q = (1.f - x2) / den;
        const float nrm = fmaxf(sqrtf(P * P * S1 + 2.f * P * Q * S2 + Q * Q * Sb), MIN_NORM_F);
        const float mxp = 1.f - PROJ_EPS_F;
        if (nrm > mxp) { const float fsc = mxp / nrm; P *= fsc; Q *= fsc; }
        bcast[0] = P; bcast[1] = Q;
    }
    __syncthreads();
    const float P = bcast[0], Q = bcast[1];

    // pass 2: exp once, store bf16 exp back into LDS, zero the pad slot
    float z = 0.f;
    for (int i = tid * 8; i < V_OUT; i += 8192) {
        ushort8_t mu = *(const ushort8_t*)&mxls[i];
        float4 b0 = *(const float4*)(bvec + i);
        float4 b1 = *(const float4*)(bvec + i + 4);
        float e0 = __expf(fmaf(P, bf2f(mu[0]), Q * b0.x));
        float e1 = __expf(fmaf(P, bf2f(mu[1]), Q * b0.y));
        float e2 = __expf(fmaf(P, bf2f(mu[2]), Q * b0.z));
        float e3 = __expf(fmaf(P, bf2f(mu[3]), Q * b0.w));
        float e4 = __expf(fmaf(P, bf2f(mu[4]), Q * b1.x));
        float e5 = __expf(fmaf(P, bf2f(mu[5]), Q * b1.y));
        float e6 = __expf(fmaf(P, bf2f(mu[6]), Q * b1.z));
        float e7 = __expf(fmaf(P, bf2f(mu[7]), Q * b1.w));
        if (i + 0 == pad) e0 = 0.f;
        if (i + 1 == pad) e1 = 0.f;
        if (i + 2 == pad) e2 = 0.f;
        if (i + 3 == pad) e3 = 0.f;
        if (i + 4 == pad) e4 = 0.f;
        if (i + 5 == pad) e5 = 0.f;
        if (i + 6 == pad) e6 = 0.f;
        if (i + 7 == pad) e7 = 0.f;
        z += ((e0 + e1) + (e2 + e3)) + ((e4 + e5) + (e6 + e7));
        ushort8_t eu;
        eu[0] = f2bf(e0); eu[1] = f2bf(e1); eu[2] = f2bf(e2); eu[3] = f2bf(e3);
        eu[4] = f2bf(e4); eu[5] = f2bf(e5); eu[6] = f2bf(e6); eu[7] = f2bf(e7);
        *(ushort8_t*)&mxls[i] = eu;
    }
    z = wave_sum(z);
    if (l == 0) red[w] = z;
    __syncthreads();
    if (tid == 0) {
        float a = 0.f;
        for (int k = 0; k < 16; ++k) a += red[k];
        bcast[2] = a;
    }
    __syncthreads();
    const float scale = (1.f - pc_arr[n]) / bcast[2];

    // pass 3: scale + write fp32 (overwrites the bf16 alias region; all reads done)
    for (int i = tid * 8; i < V_OUT; i += 8192) {
        ushort8_t eu = *(const ushort8_t*)&mxls[i];
        float4 o0, o1;
        o0.x = bf2f(eu[0]) * scale; o0.y = bf2f(eu[1]) * scale;
        o0.z = bf2f(eu[2]) * scale; o0.w = bf2f(eu[3]) * scale;
        o1.x = bf2f(eu[4]) * scale; o1.y = bf2f(eu[5]) * scale;
        o1.z = bf2f(eu[6]) * scale; o1.w = bf2f(eu[7]) * scale;
        *(float4*)(row + i) = o0;
        *(float4*)(row + i + 4) = o1;
    }
}

// ---------------- copy path: out[t*32+b][32000+c] = pc * sum_s attn[t*32+b][s]*src[s][b][c] ----
__global__ __launch_bounds__(128)
void copy_einsum(const float* __restrict__ attn, const float* __restrict__ src_map,
                 const float* __restrict__ pc_arr, float* __restrict__ Cout) {
    __shared__ float atile[32][128];
    const int tid = threadIdx.x;
    const int cc = blockIdx.x;        // 0..3  (c chunk of 128)
    const int b  = blockIdx.y;        // 0..31
    const int t0 = blockIdx.z * 32;   // 0 or 32
    const int c = cc * 128 + tid;
    const bool cv = (c < CVOC);

    float acc[32];
#pragma unroll
    for (int t = 0; t < 32; ++t) acc[t] = 0.f;

    for (int s0 = 0; s0 < SLEN_C; s0 += 128) {
        __syncthreads();
        for (int idx = tid; idx < 32 * 128; idx += 128) {
            const int t = idx >> 7, s = idx & 127;
            atile[t][s] = attn[(size_t)((t0 + t) * BATCH_C + b) * SLEN_C + s0 + s];
        }
        __syncthreads();
        for (int j = 0; j < 128; j += 4) {
            float sv0 = 0.f, sv1 = 0.f, sv2 = 0.f, sv3 = 0.f;
            if (cv) {
                const float* sp = src_map + (size_t)(s0 + j) * (BATCH_C * CVOC) + b * CVOC + c;
                sv0 = sp[0];
                sv1 = sp[BATCH_C * CVOC];
                sv2 = sp[2 * BATCH_C * CVOC];
                sv3 = sp[3 * BATCH_C * CVOC];
            }
#pragma unroll
            for (int t = 0; t < 32; ++t) {
                const float4 av = *(const float4*)&atile[t][j];
                acc[t] = fmaf(av.x, sv0, acc[t]);
                acc[t] = fmaf(av.y, sv1, acc[t]);
                acc[t] = fmaf(av.z, sv2, acc[t]);
                acc[t] = fmaf(av.w, sv3, acc[t]);
            }
        }
    }
    if (cv) {
#pragma unroll
        for (int t = 0; t < 32; ++t) {
            const int n = (t0 + t) * BATCH_C + b;
            Cout[(size_t)n * OUT_COLS + V_OUT + c] = acc[t] * pc_arr[n];
        }
    }
}

extern "C" void kernel_launch(void* const* d_in, const int* in_sizes, int n_in,
                              void* d_out, int out_size, void* d_ws, size_t ws_size,
                              hipStream_t stream) {
    const float* hidden  = (const float*)d_in[0];
    const float* attn    = (const float*)d_in[1];
    const float* src_map = (const float*)d_in[2];
    const float* W       = (const float*)d_in[3];
    const float* bvec    = (const float*)d_in[4];
    const float* Wc      = (const float*)d_in[5];
    const float* bc      = (const float*)d_in[6];
    const int*   padp    = (const int*)d_in[7];
    float* out = (float*)d_out;

    const int wb_elems = V_OUT * D_IN;    // 32,768,000
    const int hb_elems = N_ROWS * D_IN;   //  2,097,152
    unsigned short* Wb = (unsigned short*)d_ws;
    unsigned short* Hb = Wb + wb_elems;
    float* g_arr  = (float*)(Hb + hb_elems);
    float* pc_arr = g_arr + N_ROWS;
    // ws bytes used: 65,536,000 + 4,194,304 + 2*8192 ~= 69.8 MB

    cast_f32_to_bf16<<<4000, 256, 0, stream>>>(W, Wb, wb_elems / 4);
    cast_f32_to_bf16<<<512, 256, 0, stream>>>(hidden, Hb, hb_elems / 4);
    row_stats<<<N_ROWS, 256, 0, stream>>>(hidden, Wc, bc, g_arr, pc_arr);

    gemm_bt_bf16<<<4000, 256, 0, stream>>>(Hb, Wb, (unsigned short*)out);

    softmax_epi<<<N_ROWS, 1024, 0, stream>>>(out, bvec, g_arr, pc_arr, padp);

    dim3 egrid(4, BATCH_C, 2);
    copy_einsum<<<egrid, 128, 0, stream>>>(attn, src_map, pc_arr, out);
}